// Round 1
// baseline (1913.429 us; speedup 1.0000x reference)
//
#include <hip/hip_runtime.h>
#include <hip/hip_bf16.h>
#include <math.h>

#define TPB 256

// ---------------- Threefry2x32 (exact JAX semantics) ----------------
__host__ __device__ inline void tf2x32(unsigned ks0, unsigned ks1,
                                       unsigned x0, unsigned x1,
                                       unsigned& o0, unsigned& o1) {
  const unsigned ks2 = ks0 ^ ks1 ^ 0x1BD11BDAu;
  unsigned v0 = x0 + ks0, v1 = x1 + ks1;
#define TF_RND(r) { v0 += v1; v1 = (v1 << (r)) | (v1 >> (32 - (r))); v1 ^= v0; }
  TF_RND(13) TF_RND(15) TF_RND(26) TF_RND(6)
  v0 += ks1; v1 += ks2 + 1u;
  TF_RND(17) TF_RND(29) TF_RND(16) TF_RND(24)
  v0 += ks2; v1 += ks0 + 2u;
  TF_RND(13) TF_RND(15) TF_RND(26) TF_RND(6)
  v0 += ks0; v1 += ks1 + 3u;
  TF_RND(17) TF_RND(29) TF_RND(16) TF_RND(24)
  v0 += ks1; v1 += ks2 + 4u;
  TF_RND(13) TF_RND(15) TF_RND(26) TF_RND(6)
  v0 += ks2; v1 += ks0 + 5u;
#undef TF_RND
  o0 = v0; o1 = v1;
}

// partitionable random_bits(32): element j -> threefry(key, (0, j)), fold o0^o1
__device__ __forceinline__ float gumbel32(unsigned k0, unsigned k1, unsigned idx) {
  unsigned o0, o1;
  tf2x32(k0, k1, 0u, idx, o0, o1);
  unsigned bits = o0 ^ o1;
  float f = __uint_as_float((bits >> 9) | 0x3f800000u) - 1.0f;
  float u = (f > 0.0f) ? f : 1.17549435e-38f;   // max(tiny, f*(1-tiny)+tiny) == this
  float w = (float)(-log((double)u));            // fp32-rounded at each stage, like ref
  return (float)(-log((double)w));
}

// ---------------- graph prep ----------------
__global__ void deg_count_kernel(const int* __restrict__ dst, int* __restrict__ deg, int E) {
  int e = blockIdx.x * blockDim.x + threadIdx.x;
  if (e < E) atomicAdd(&deg[dst[e]], 1);
}

__global__ void dinv_kernel(const int* __restrict__ deg, float* __restrict__ dinv,
                            float* __restrict__ dinv2, int N) {
  int n = blockIdx.x * blockDim.x + threadIdx.x;
  if (n >= N) return;
  float d = (float)(deg[n] + 1);
  float di = 1.0f / sqrtf(d);
  dinv[n] = di;
  dinv2[n] = di * di;
}

// ---------------- dense ops (fp64 accumulate, fp32 materialize) ----------------
template <int K, int J>
__global__ void matmul_kernel(const float* __restrict__ A, const float* __restrict__ W,
                              float* __restrict__ out, int N) {
  int t = blockIdx.x * blockDim.x + threadIdx.x;
  if (t >= N * J) return;
  int n = t / J, j = t % J;
  const float* a = A + (size_t)n * K;
  double acc = 0.0;
  for (int k = 0; k < K; ++k) acc += (double)a[k] * (double)W[k * J + j];
  out[(size_t)n * J + j] = (float)acc;
}

template <int J>
__global__ void edge_agg_kernel(const int* __restrict__ src, const int* __restrict__ dst,
                                const float* __restrict__ dinv, const float* __restrict__ h,
                                double* __restrict__ agg, int E) {
  int t = blockIdx.x * blockDim.x + threadIdx.x;
  if (t >= E * J) return;
  int e = t / J, j = t % J;
  int s = src[e], d = dst[e];
  float norm = dinv[s] * dinv[d];                  // fp32, matches ref materialization
  double v = (double)h[(size_t)s * J + j] * (double)norm;
#ifdef __HIP_PLATFORM_AMD__
  unsafeAtomicAdd(&agg[(size_t)d * J + j], v);     // hw global_atomic_add_f64
#else
  atomicAdd(&agg[(size_t)d * J + j], v);
#endif
}

template <int J>
__global__ void finalize_kernel(const double* __restrict__ agg, const float* __restrict__ h,
                                const float* __restrict__ dinv2, const float* __restrict__ b,
                                float* __restrict__ out, int N) {
  int t = blockIdx.x * blockDim.x + threadIdx.x;
  if (t >= N * J) return;
  int n = t / J, j = t % J;
  double v = agg[t] + (double)h[t] * (double)dinv2[n];
  out[t] = (float)v + b[j];
}

// ---------------- heads ----------------
__global__ void head_start_kernel(const float* __restrict__ h,
                                  const float* __restrict__ Ws1, const float* __restrict__ bs1,
                                  const float* __restrict__ Ws2, const float* __restrict__ bs2,
                                  int* __restrict__ outw, int N, unsigned k0, unsigned k1) {
  int n = blockIdx.x * blockDim.x + threadIdx.x;
  if (n >= N) return;
  float hr[32];
#pragma unroll
  for (int i = 0; i < 32; ++i) hr[i] = h[(size_t)n * 32 + i];
  float hid[16];
#pragma unroll
  for (int j = 0; j < 16; ++j) {
    double a = 0.0;
#pragma unroll
    for (int k = 0; k < 32; ++k) a += (double)hr[k] * (double)Ws1[k * 16 + j];
    float v = (float)a + bs1[j];
    hid[j] = fminf(fmaxf(v, 0.0f), 6.0f);
  }
  int best = 0;
  float bz = -INFINITY;
  for (int c = 0; c < 32; ++c) {
    double a = 0.0;
#pragma unroll
    for (int k = 0; k < 16; ++k) a += (double)hid[k] * (double)Ws2[k * 32 + c];
    float logit = (float)a + bs2[c];
    float z = logit + gumbel32(k0, k1, (unsigned)(n * 32 + c));
    if (z > bz) { bz = z; best = c; }   // first-occurrence argmax
  }
  outw[n] = best;
}

__global__ void head_end_kernel(const float* __restrict__ h, const int* __restrict__ start,
                                const float* __restrict__ We1, const float* __restrict__ be1,
                                const float* __restrict__ We2, const float* __restrict__ be2,
                                int* __restrict__ oute, int N, unsigned k0, unsigned k1) {
  int r = blockIdx.x * blockDim.x + threadIdx.x;
  if (r >= 2 * N) return;
  int row = (r < N) ? r : start[r - N];
  float hr[32];
#pragma unroll
  for (int i = 0; i < 32; ++i) hr[i] = h[(size_t)row * 32 + i];
  float hid[24];
#pragma unroll
  for (int j = 0; j < 24; ++j) {
    double a = 0.0;
#pragma unroll
    for (int k = 0; k < 32; ++k) a += (double)hr[k] * (double)We1[k * 24 + j];
    float v = (float)a + be1[j];
    hid[j] = fminf(fmaxf(v, 0.0f), 6.0f);
  }
  int best = 0;
  float bz = -INFINITY;
  for (int c = 0; c < 32; ++c) {
    double a = 0.0;
#pragma unroll
    for (int k = 0; k < 24; ++k) a += (double)hid[k] * (double)We2[k * 32 + c];
    float logit = (float)a + be2[c];
    float z = logit + gumbel32(k0, k1, (unsigned)(r * 32 + c));
    if (z > bz) { bz = z; best = c; }
  }
  oute[r] = best;
}

// ---------------- launch ----------------
extern "C" void kernel_launch(void* const* d_in, const int* in_sizes, int n_in,
                              void* d_out, int out_size, void* d_ws, size_t ws_size,
                              hipStream_t stream) {
  const float* x   = (const float*)d_in[0];
  const int*   ei  = (const int*)d_in[1];     // [2, E] int32
  const float* W1  = (const float*)d_in[3];
  const float* b1  = (const float*)d_in[4];
  const float* W2  = (const float*)d_in[5];
  const float* b2  = (const float*)d_in[6];
  const float* W3  = (const float*)d_in[7];
  const float* b3  = (const float*)d_in[8];
  const float* Ws1 = (const float*)d_in[9];
  const float* bs1 = (const float*)d_in[10];
  const float* Ws2 = (const float*)d_in[11];
  const float* bs2 = (const float*)d_in[12];
  const float* We1 = (const float*)d_in[13];
  const float* be1 = (const float*)d_in[14];
  const float* We2 = (const float*)d_in[15];
  const float* be2 = (const float*)d_in[16];

  const int N = in_sizes[0] / 128;
  const int E = in_sizes[1] / 2;
  const int* srcv = ei;
  const int* dstv = ei + E;

  char* ws = (char*)d_ws;
  size_t off = 0;
  double* agg  = (double*)(ws + off); off += (size_t)N * 32 * 8;
  float* hA    = (float*)(ws + off);  off += (size_t)N * 32 * 4;
  float* hB    = (float*)(ws + off);  off += (size_t)N * 32 * 4;
  float* dinv  = (float*)(ws + off);  off += (size_t)N * 4;
  float* dinv2 = (float*)(ws + off);  off += (size_t)N * 4;
  int*   deg   = (int*)(ws + off);    off += (size_t)N * 4;

  // split(key(42), 2), partitionable/foldlike: subkey i = threefry(key,(0,i))
  unsigned k1a, k1b, k2a, k2b;
  tf2x32(0u, 42u, 0u, 0u, k1a, k1b);
  tf2x32(0u, 42u, 0u, 1u, k2a, k2b);

  hipMemsetAsync(deg, 0, (size_t)N * 4, stream);
  deg_count_kernel<<<(E + TPB - 1) / TPB, TPB, 0, stream>>>(dstv, deg, E);
  dinv_kernel<<<(N + TPB - 1) / TPB, TPB, 0, stream>>>(deg, dinv, dinv2, N);

  // Layer 1: 128 -> 16
  matmul_kernel<128, 16><<<((size_t)N * 16 + TPB - 1) / TPB, TPB, 0, stream>>>(x, W1, hA, N);
  hipMemsetAsync(agg, 0, (size_t)N * 16 * 8, stream);
  edge_agg_kernel<16><<<((size_t)E * 16 + TPB - 1) / TPB, TPB, 0, stream>>>(srcv, dstv, dinv, hA, agg, E);
  finalize_kernel<16><<<((size_t)N * 16 + TPB - 1) / TPB, TPB, 0, stream>>>(agg, hA, dinv2, b1, hA, N);

  // Layer 2: 16 -> 24
  matmul_kernel<16, 24><<<((size_t)N * 24 + TPB - 1) / TPB, TPB, 0, stream>>>(hA, W2, hB, N);
  hipMemsetAsync(agg, 0, (size_t)N * 24 * 8, stream);
  edge_agg_kernel<24><<<((size_t)E * 24 + TPB - 1) / TPB, TPB, 0, stream>>>(srcv, dstv, dinv, hB, agg, E);
  finalize_kernel<24><<<((size_t)N * 24 + TPB - 1) / TPB, TPB, 0, stream>>>(agg, hB, dinv2, b2, hB, N);

  // Layer 3: 24 -> 32
  matmul_kernel<24, 32><<<((size_t)N * 32 + TPB - 1) / TPB, TPB, 0, stream>>>(hB, W3, hA, N);
  hipMemsetAsync(agg, 0, (size_t)N * 32 * 8, stream);
  edge_agg_kernel<32><<<((size_t)E * 32 + TPB - 1) / TPB, TPB, 0, stream>>>(srcv, dstv, dinv, hA, agg, E);
  finalize_kernel<32><<<((size_t)N * 32 + TPB - 1) / TPB, TPB, 0, stream>>>(agg, hA, dinv2, b3, hA, N);

  // Heads
  int* outI = (int*)d_out;
  head_start_kernel<<<(N + TPB - 1) / TPB, TPB, 0, stream>>>(hA, Ws1, bs1, Ws2, bs2, outI, N, k1a, k1b);
  head_end_kernel<<<(2 * N + TPB - 1) / TPB, TPB, 0, stream>>>(hA, outI, We1, be1, We2, be2, outI + N, N, k2a, k2b);
}

// Round 2
// 1638.032 us; speedup vs baseline: 1.1681x; 1.1681x over previous
//
#include <hip/hip_runtime.h>
#include <hip/hip_bf16.h>
#include <math.h>

#define TPB 256

// ---------------- Threefry2x32 (exact JAX semantics) ----------------
__host__ __device__ inline void tf2x32(unsigned ks0, unsigned ks1,
                                       unsigned x0, unsigned x1,
                                       unsigned& o0, unsigned& o1) {
  const unsigned ks2 = ks0 ^ ks1 ^ 0x1BD11BDAu;
  unsigned v0 = x0 + ks0, v1 = x1 + ks1;
#define TF_RND(r) { v0 += v1; v1 = (v1 << (r)) | (v1 >> (32 - (r))); v1 ^= v0; }
  TF_RND(13) TF_RND(15) TF_RND(26) TF_RND(6)
  v0 += ks1; v1 += ks2 + 1u;
  TF_RND(17) TF_RND(29) TF_RND(16) TF_RND(24)
  v0 += ks2; v1 += ks0 + 2u;
  TF_RND(13) TF_RND(15) TF_RND(26) TF_RND(6)
  v0 += ks0; v1 += ks1 + 3u;
  TF_RND(17) TF_RND(29) TF_RND(16) TF_RND(24)
  v0 += ks1; v1 += ks2 + 4u;
  TF_RND(13) TF_RND(15) TF_RND(26) TF_RND(6)
  v0 += ks2; v1 += ks0 + 5u;
#undef TF_RND
  o0 = v0; o1 = v1;
}

// partitionable random_bits(32): element j -> threefry(key, (0, j)), fold o0^o1
__device__ __forceinline__ float gumbel32(unsigned k0, unsigned k1, unsigned idx) {
  unsigned o0, o1;
  tf2x32(k0, k1, 0u, idx, o0, o1);
  unsigned bits = o0 ^ o1;
  float f = __uint_as_float((bits >> 9) | 0x3f800000u) - 1.0f;
  float u = (f > 0.0f) ? f : 1.17549435e-38f;
  float w = (float)(-log((double)u));            // fp32-rounded at each stage, like ref
  return (float)(-log((double)w));
}

// ---------------- graph prep ----------------
__global__ void deg_count_kernel(const int* __restrict__ dst, int* __restrict__ deg, int E) {
  int e = blockIdx.x * blockDim.x + threadIdx.x;
  if (e < E) atomicAdd(&deg[dst[e]], 1);
}

__global__ void dinv_kernel(const int* __restrict__ deg, float* __restrict__ dinv,
                            float* __restrict__ dinv2, int N) {
  int n = blockIdx.x * blockDim.x + threadIdx.x;
  if (n >= N) return;
  float d = (float)(deg[n] + 1);
  float di = 1.0f / sqrtf(d);
  dinv[n] = di;
  dinv2[n] = di * di;
}

// ---- exclusive scan of deg -> rowptr (N=100k; 256 chunks, 1-block scan) ----
__global__ void scan_chunks_kernel(const int* __restrict__ deg, int* __restrict__ chunkbase,
                                   int N, int chunk) {
  __shared__ int sh[TPB];
  int t = threadIdx.x;
  int beg = t * chunk, end = min(beg + chunk, N);
  int s = 0;
  for (int i = beg; i < end; ++i) s += deg[i];
  sh[t] = s;
  __syncthreads();
  // simple inclusive scan in LDS
  for (int ofs = 1; ofs < TPB; ofs <<= 1) {
    int v = (t >= ofs) ? sh[t - ofs] : 0;
    __syncthreads();
    sh[t] += v;
    __syncthreads();
  }
  chunkbase[t] = (t == 0) ? 0 : sh[t - 1];   // exclusive
}

__global__ void fill_rowptr_kernel(const int* __restrict__ deg, const int* __restrict__ chunkbase,
                                   int* __restrict__ rowptr, int* __restrict__ cursor,
                                   int N, int E, int chunk) {
  int t = threadIdx.x;
  int beg = t * chunk, end = min(beg + chunk, N);
  int run = chunkbase[t];
  for (int n = beg; n < end; ++n) {
    rowptr[n] = run;
    cursor[n] = run;
    run += deg[n];
  }
  if (t == TPB - 1) rowptr[N] = E;
}

__global__ void csr_fill_kernel(const int* __restrict__ src, const int* __restrict__ dst,
                                const float* __restrict__ dinv,
                                int* __restrict__ cursor,
                                int* __restrict__ csr_src, float* __restrict__ csr_norm, int E) {
  int e = blockIdx.x * blockDim.x + threadIdx.x;
  if (e >= E) return;
  int s = src[e], d = dst[e];
  int pos = atomicAdd(&cursor[d], 1);
  csr_src[pos] = s;
  csr_norm[pos] = dinv[s] * dinv[d];   // fp32, matches ref materialization
}

// ---------------- dense ops (fp64 accumulate, fp32 materialize) ----------------
template <int K, int J>
__global__ void matmul_kernel(const float* __restrict__ A, const float* __restrict__ W,
                              float* __restrict__ out, int N) {
  int t = blockIdx.x * blockDim.x + threadIdx.x;
  if (t >= N * J) return;
  int n = t / J, j = t % J;
  const float* a = A + (size_t)n * K;
  double acc = 0.0;
  for (int k = 0; k < K; ++k) acc += (double)a[k] * (double)W[k * J + j];
  out[(size_t)n * J + j] = (float)acc;
}

// gather-style aggregation + self-loop + bias (replaces edge_agg + finalize)
template <int J>
__global__ void gather_agg_kernel(const int* __restrict__ rowptr,
                                  const int* __restrict__ csr_src,
                                  const float* __restrict__ csr_norm,
                                  const float* __restrict__ h,
                                  const float* __restrict__ dinv2,
                                  const float* __restrict__ b,
                                  float* __restrict__ out, int N) {
  int t = blockIdx.x * blockDim.x + threadIdx.x;
  int n = t / J, j = t % J;
  if (n >= N) return;
  int beg = rowptr[n], end = rowptr[n + 1];
  double acc = 0.0;
  for (int i = beg; i < end; ++i) {
    int s = csr_src[i];
    float w = csr_norm[i];
    acc += (double)h[(size_t)s * J + j] * (double)w;
  }
  acc += (double)h[(size_t)n * J + j] * (double)dinv2[n];
  out[(size_t)n * J + j] = (float)acc + b[j];
}

// ---------------- heads ----------------
__global__ void head_start_kernel(const float* __restrict__ h,
                                  const float* __restrict__ Ws1, const float* __restrict__ bs1,
                                  const float* __restrict__ Ws2, const float* __restrict__ bs2,
                                  int* __restrict__ outw, int N, unsigned k0, unsigned k1) {
  int n = blockIdx.x * blockDim.x + threadIdx.x;
  if (n >= N) return;
  float hr[32];
#pragma unroll
  for (int i = 0; i < 32; ++i) hr[i] = h[(size_t)n * 32 + i];
  float hid[16];
#pragma unroll
  for (int j = 0; j < 16; ++j) {
    double a = 0.0;
#pragma unroll
    for (int k = 0; k < 32; ++k) a += (double)hr[k] * (double)Ws1[k * 16 + j];
    float v = (float)a + bs1[j];
    hid[j] = fminf(fmaxf(v, 0.0f), 6.0f);
  }
  int best = 0;
  float bz = -INFINITY;
  for (int c = 0; c < 32; ++c) {
    double a = 0.0;
#pragma unroll
    for (int k = 0; k < 16; ++k) a += (double)hid[k] * (double)Ws2[k * 32 + c];
    float logit = (float)a + bs2[c];
    float z = logit + gumbel32(k0, k1, (unsigned)(n * 32 + c));
    if (z > bz) { bz = z; best = c; }   // first-occurrence argmax
  }
  outw[n] = best;
}

__global__ void head_end_kernel(const float* __restrict__ h, const int* __restrict__ start,
                                const float* __restrict__ We1, const float* __restrict__ be1,
                                const float* __restrict__ We2, const float* __restrict__ be2,
                                int* __restrict__ oute, int N, unsigned k0, unsigned k1) {
  int r = blockIdx.x * blockDim.x + threadIdx.x;
  if (r >= 2 * N) return;
  int row = (r < N) ? r : start[r - N];
  float hr[32];
#pragma unroll
  for (int i = 0; i < 32; ++i) hr[i] = h[(size_t)row * 32 + i];
  float hid[24];
#pragma unroll
  for (int j = 0; j < 24; ++j) {
    double a = 0.0;
#pragma unroll
    for (int k = 0; k < 32; ++k) a += (double)hr[k] * (double)We1[k * 24 + j];
    float v = (float)a + be1[j];
    hid[j] = fminf(fmaxf(v, 0.0f), 6.0f);
  }
  int best = 0;
  float bz = -INFINITY;
  for (int c = 0; c < 32; ++c) {
    double a = 0.0;
#pragma unroll
    for (int k = 0; k < 24; ++k) a += (double)hid[k] * (double)We2[k * 32 + c];
    float logit = (float)a + be2[c];
    float z = logit + gumbel32(k0, k1, (unsigned)(r * 32 + c));
    if (z > bz) { bz = z; best = c; }
  }
  oute[r] = best;
}

// ---------------- launch ----------------
extern "C" void kernel_launch(void* const* d_in, const int* in_sizes, int n_in,
                              void* d_out, int out_size, void* d_ws, size_t ws_size,
                              hipStream_t stream) {
  const float* x   = (const float*)d_in[0];
  const int*   ei  = (const int*)d_in[1];     // [2, E] int32
  const float* W1  = (const float*)d_in[3];
  const float* b1  = (const float*)d_in[4];
  const float* W2  = (const float*)d_in[5];
  const float* b2  = (const float*)d_in[6];
  const float* W3  = (const float*)d_in[7];
  const float* b3  = (const float*)d_in[8];
  const float* Ws1 = (const float*)d_in[9];
  const float* bs1 = (const float*)d_in[10];
  const float* Ws2 = (const float*)d_in[11];
  const float* bs2 = (const float*)d_in[12];
  const float* We1 = (const float*)d_in[13];
  const float* be1 = (const float*)d_in[14];
  const float* We2 = (const float*)d_in[15];
  const float* be2 = (const float*)d_in[16];

  const int N = in_sizes[0] / 128;
  const int E = in_sizes[1] / 2;
  const int* srcv = ei;
  const int* dstv = ei + E;

  char* ws = (char*)d_ws;
  size_t off = 0;
  float* hA     = (float*)(ws + off); off += (size_t)N * 32 * 4;
  float* hB     = (float*)(ws + off); off += (size_t)N * 32 * 4;
  int*   csr_src  = (int*)(ws + off);   off += (size_t)E * 4;
  float* csr_norm = (float*)(ws + off); off += (size_t)E * 4;
  float* dinv   = (float*)(ws + off); off += (size_t)N * 4;
  float* dinv2  = (float*)(ws + off); off += (size_t)N * 4;
  int*   deg    = (int*)(ws + off);   off += (size_t)N * 4;
  int*   rowptr = (int*)(ws + off);   off += (size_t)(N + 1) * 4;
  int*   cursor = (int*)(ws + off);   off += (size_t)N * 4;
  int*   chunkbase = (int*)(ws + off); off += (size_t)TPB * 4;

  unsigned k1a, k1b, k2a, k2b;
  tf2x32(0u, 42u, 0u, 0u, k1a, k1b);
  tf2x32(0u, 42u, 0u, 1u, k2a, k2b);

  const int chunk = (N + TPB - 1) / TPB;

  hipMemsetAsync(deg, 0, (size_t)N * 4, stream);
  deg_count_kernel<<<(E + TPB - 1) / TPB, TPB, 0, stream>>>(dstv, deg, E);
  dinv_kernel<<<(N + TPB - 1) / TPB, TPB, 0, stream>>>(deg, dinv, dinv2, N);
  scan_chunks_kernel<<<1, TPB, 0, stream>>>(deg, chunkbase, N, chunk);
  fill_rowptr_kernel<<<1, TPB, 0, stream>>>(deg, chunkbase, rowptr, cursor, N, E, chunk);
  csr_fill_kernel<<<(E + TPB - 1) / TPB, TPB, 0, stream>>>(srcv, dstv, dinv, cursor,
                                                           csr_src, csr_norm, E);

  // Layer 1: 128 -> 16   (x -> hA -> hB)
  matmul_kernel<128, 16><<<((size_t)N * 16 + TPB - 1) / TPB, TPB, 0, stream>>>(x, W1, hA, N);
  gather_agg_kernel<16><<<((size_t)N * 16 + TPB - 1) / TPB, TPB, 0, stream>>>(
      rowptr, csr_src, csr_norm, hA, dinv2, b1, hB, N);

  // Layer 2: 16 -> 24    (hB -> hA -> hB)
  matmul_kernel<16, 24><<<((size_t)N * 24 + TPB - 1) / TPB, TPB, 0, stream>>>(hB, W2, hA, N);
  gather_agg_kernel<24><<<((size_t)N * 24 + TPB - 1) / TPB, TPB, 0, stream>>>(
      rowptr, csr_src, csr_norm, hA, dinv2, b2, hB, N);

  // Layer 3: 24 -> 32    (hB -> hA -> hB)
  matmul_kernel<24, 32><<<((size_t)N * 32 + TPB - 1) / TPB, TPB, 0, stream>>>(hB, W3, hA, N);
  gather_agg_kernel<32><<<((size_t)N * 32 + TPB - 1) / TPB, TPB, 0, stream>>>(
      rowptr, csr_src, csr_norm, hA, dinv2, b3, hB, N);

  // Heads
  int* outI = (int*)d_out;
  head_start_kernel<<<(N + TPB - 1) / TPB, TPB, 0, stream>>>(hB, Ws1, bs1, Ws2, bs2, outI, N, k1a, k1b);
  head_end_kernel<<<(2 * N + TPB - 1) / TPB, TPB, 0, stream>>>(hB, outI, We1, be1, We2, be2, outI + N, N, k2a, k2b);
}

// Round 3
// 1366.236 us; speedup vs baseline: 1.4005x; 1.1989x over previous
//
#include <hip/hip_runtime.h>
#include <hip/hip_bf16.h>
#include <math.h>

#define TPB 256

// ---------------- Threefry2x32 (exact JAX semantics) ----------------
__host__ __device__ inline void tf2x32(unsigned ks0, unsigned ks1,
                                       unsigned x0, unsigned x1,
                                       unsigned& o0, unsigned& o1) {
  const unsigned ks2 = ks0 ^ ks1 ^ 0x1BD11BDAu;
  unsigned v0 = x0 + ks0, v1 = x1 + ks1;
#define TF_RND(r) { v0 += v1; v1 = (v1 << (r)) | (v1 >> (32 - (r))); v1 ^= v0; }
  TF_RND(13) TF_RND(15) TF_RND(26) TF_RND(6)
  v0 += ks1; v1 += ks2 + 1u;
  TF_RND(17) TF_RND(29) TF_RND(16) TF_RND(24)
  v0 += ks2; v1 += ks0 + 2u;
  TF_RND(13) TF_RND(15) TF_RND(26) TF_RND(6)
  v0 += ks0; v1 += ks1 + 3u;
  TF_RND(17) TF_RND(29) TF_RND(16) TF_RND(24)
  v0 += ks1; v1 += ks2 + 4u;
  TF_RND(13) TF_RND(15) TF_RND(26) TF_RND(6)
  v0 += ks2; v1 += ks0 + 5u;
#undef TF_RND
  o0 = v0; o1 = v1;
}

// partitionable random_bits(32): element j -> threefry(key, (0, j)), fold o0^o1
__device__ __forceinline__ float gumbel32(unsigned k0, unsigned k1, unsigned idx) {
  unsigned o0, o1;
  tf2x32(k0, k1, 0u, idx, o0, o1);
  unsigned bits = o0 ^ o1;
  float f = __uint_as_float((bits >> 9) | 0x3f800000u) - 1.0f;
  float u = (f > 0.0f) ? f : 1.17549435e-38f;
  float w = (float)(-log((double)u));            // fp32-rounded at each stage, like ref
  return (float)(-log((double)w));
}

// ---------------- graph prep ----------------
__global__ void deg_count_kernel(const int* __restrict__ dst, int* __restrict__ deg, int E) {
  int e = blockIdx.x * blockDim.x + threadIdx.x;
  if (e < E) atomicAdd(&deg[dst[e]], 1);
}

__global__ void dinv_kernel(const int* __restrict__ deg, float* __restrict__ dinv,
                            float* __restrict__ dinv2, int N) {
  int n = blockIdx.x * blockDim.x + threadIdx.x;
  if (n >= N) return;
  float d = (float)(deg[n] + 1);
  float di = 1.0f / sqrtf(d);
  dinv[n] = di;
  dinv2[n] = di * di;
}

// ---- exclusive scan of deg -> rowptr (N=100k; 256 chunks, 1-block scan) ----
__global__ void scan_chunks_kernel(const int* __restrict__ deg, int* __restrict__ chunkbase,
                                   int N, int chunk) {
  __shared__ int sh[TPB];
  int t = threadIdx.x;
  int beg = t * chunk, end = min(beg + chunk, N);
  int s = 0;
  for (int i = beg; i < end; ++i) s += deg[i];
  sh[t] = s;
  __syncthreads();
  for (int ofs = 1; ofs < TPB; ofs <<= 1) {
    int v = (t >= ofs) ? sh[t - ofs] : 0;
    __syncthreads();
    sh[t] += v;
    __syncthreads();
  }
  chunkbase[t] = (t == 0) ? 0 : sh[t - 1];   // exclusive
}

__global__ void fill_rowptr_kernel(const int* __restrict__ deg, const int* __restrict__ chunkbase,
                                   int* __restrict__ rowptr, int* __restrict__ cursor,
                                   int N, int E, int chunk) {
  int t = threadIdx.x;
  int beg = t * chunk, end = min(beg + chunk, N);
  int run = chunkbase[t];
  for (int n = beg; n < end; ++n) {
    rowptr[n] = run;
    cursor[n] = run;
    run += deg[n];
  }
  if (t == TPB - 1) rowptr[N] = E;
}

__global__ void csr_fill_kernel(const int* __restrict__ src, const int* __restrict__ dst,
                                const float* __restrict__ dinv,
                                int* __restrict__ cursor,
                                int* __restrict__ csr_src, float* __restrict__ csr_norm, int E) {
  int e = blockIdx.x * blockDim.x + threadIdx.x;
  if (e >= E) return;
  int s = src[e], d = dst[e];
  int pos = atomicAdd(&cursor[d], 1);
  csr_src[pos] = s;
  csr_norm[pos] = dinv[s] * dinv[d];   // fp32, matches ref materialization
}

// ---------------- dense ops (fp64 accumulate, fp32 materialize) ----------------
template <int K, int J>
__global__ void matmul_kernel(const float* __restrict__ A, const float* __restrict__ W,
                              float* __restrict__ out, int N) {
  int t = blockIdx.x * blockDim.x + threadIdx.x;
  if (t >= N * J) return;
  int n = t / J, j = t % J;
  const float* a = A + (size_t)n * K;
  double acc = 0.0;
  for (int k = 0; k < K; ++k) acc += (double)a[k] * (double)W[k * J + j];
  out[(size_t)n * J + j] = (float)acc;
}

// gather-style aggregation + self-loop + bias
template <int J>
__global__ void gather_agg_kernel(const int* __restrict__ rowptr,
                                  const int* __restrict__ csr_src,
                                  const float* __restrict__ csr_norm,
                                  const float* __restrict__ h,
                                  const float* __restrict__ dinv2,
                                  const float* __restrict__ b,
                                  float* __restrict__ out, int N) {
  int t = blockIdx.x * blockDim.x + threadIdx.x;
  int n = t / J, j = t % J;
  if (n >= N) return;
  int beg = rowptr[n], end = rowptr[n + 1];
  double acc = 0.0;
  for (int i = beg; i < end; ++i) {
    int s = csr_src[i];
    float w = csr_norm[i];
    acc += (double)h[(size_t)s * J + j] * (double)w;
  }
  acc += (double)h[(size_t)n * J + j] * (double)dinv2[n];
  out[(size_t)n * J + j] = (float)acc + b[j];
}

// ---------------- heads (phase 1: hidden layers, exact fp32 materialization) ----
// start head hidden: [N,32] @ Ws1[32,16] + bs1 -> relu6 -> hid [N,16]
__global__ void hid_start_kernel(const float* __restrict__ h,
                                 const float* __restrict__ Ws1, const float* __restrict__ bs1,
                                 float* __restrict__ hid, int N) {
  int t = blockIdx.x * blockDim.x + threadIdx.x;
  if (t >= N * 16) return;
  int n = t / 16, j = t % 16;
  const float* hr = h + (size_t)n * 32;
  double a = 0.0;
#pragma unroll
  for (int k = 0; k < 32; ++k) a += (double)hr[k] * (double)Ws1[k * 16 + j];
  float v = (float)a + bs1[j];
  hid[t] = fminf(fmaxf(v, 0.0f), 6.0f);
}

// end head hidden: rows r<N use h[r], rows r>=N use h[start[r-N]]
__global__ void hid_end_kernel(const float* __restrict__ h, const int* __restrict__ start,
                               const float* __restrict__ We1, const float* __restrict__ be1,
                               float* __restrict__ hid, int N) {
  int t = blockIdx.x * blockDim.x + threadIdx.x;
  if (t >= 2 * N * 24) return;
  int r = t / 24, j = t % 24;
  int row = (r < N) ? r : start[r - N];
  const float* hr = h + (size_t)row * 32;
  double a = 0.0;
#pragma unroll
  for (int k = 0; k < 32; ++k) a += (double)hr[k] * (double)We1[k * 24 + j];
  float v = (float)a + be1[j];
  hid[t] = fminf(fmaxf(v, 0.0f), 6.0f);
}

// ---------------- heads (phase 2: logits + gumbel + wave argmax) ----------------
// thread = (row, class); 32 classes per 32-lane group; 2 rows per wave64.
template <int K>
__global__ void pick_kernel(const float* __restrict__ hid,
                            const float* __restrict__ W2, const float* __restrict__ b2,
                            int* __restrict__ outw, int R, unsigned k0, unsigned k1) {
  int t = blockIdx.x * blockDim.x + threadIdx.x;
  int r = t >> 5;            // row
  int c = t & 31;            // class
  if (r >= R) return;
  const float* hr = hid + (size_t)r * K;
  double a = 0.0;
#pragma unroll
  for (int k = 0; k < K; ++k) a += (double)hr[k] * (double)W2[k * 32 + c];
  float logit = (float)a + b2[c];
  float z = logit + gumbel32(k0, k1, (unsigned)(r * 32 + c));
  int best = c;
  // butterfly argmax over the 32-lane class group; tie -> lower class (first occurrence)
#pragma unroll
  for (int m = 16; m >= 1; m >>= 1) {
    float oz = __shfl_xor(z, m, 32);
    int   ob = __shfl_xor(best, m, 32);
    if (oz > z || (oz == z && ob < best)) { z = oz; best = ob; }
  }
  if (c == 0) outw[r] = best;
}

// ---------------- launch ----------------
extern "C" void kernel_launch(void* const* d_in, const int* in_sizes, int n_in,
                              void* d_out, int out_size, void* d_ws, size_t ws_size,
                              hipStream_t stream) {
  const float* x   = (const float*)d_in[0];
  const int*   ei  = (const int*)d_in[1];     // [2, E] int32
  const float* W1  = (const float*)d_in[3];
  const float* b1  = (const float*)d_in[4];
  const float* W2  = (const float*)d_in[5];
  const float* b2  = (const float*)d_in[6];
  const float* W3  = (const float*)d_in[7];
  const float* b3  = (const float*)d_in[8];
  const float* Ws1 = (const float*)d_in[9];
  const float* bs1 = (const float*)d_in[10];
  const float* Ws2 = (const float*)d_in[11];
  const float* bs2 = (const float*)d_in[12];
  const float* We1 = (const float*)d_in[13];
  const float* be1 = (const float*)d_in[14];
  const float* We2 = (const float*)d_in[15];
  const float* be2 = (const float*)d_in[16];

  const int N = in_sizes[0] / 128;
  const int E = in_sizes[1] / 2;
  const int* srcv = ei;
  const int* dstv = ei + E;

  char* ws = (char*)d_ws;
  size_t off = 0;
  float* hA     = (float*)(ws + off); off += (size_t)N * 32 * 4;
  float* hB     = (float*)(ws + off); off += (size_t)N * 32 * 4;
  int*   csr_src  = (int*)(ws + off);   off += (size_t)E * 4;
  float* csr_norm = (float*)(ws + off); off += (size_t)E * 4;
  float* dinv   = (float*)(ws + off); off += (size_t)N * 4;
  float* dinv2  = (float*)(ws + off); off += (size_t)N * 4;
  int*   deg    = (int*)(ws + off);   off += (size_t)N * 4;
  int*   rowptr = (int*)(ws + off);   off += (size_t)(N + 1) * 4;
  int*   cursor = (int*)(ws + off);   off += (size_t)N * 4;
  int*   chunkbase = (int*)(ws + off); off += (size_t)TPB * 4;
  // head-phase overlays (CSR + hA are dead by the time these are used)
  float* hid_start = hA;                       // N*16 fp32 fits in hA (N*32)
  float* hid_end   = (float*)csr_src;          // 2N*24*4 = 19.2MB fits in csr region (25.6MB)

  unsigned k1a, k1b, k2a, k2b;
  tf2x32(0u, 42u, 0u, 0u, k1a, k1b);
  tf2x32(0u, 42u, 0u, 1u, k2a, k2b);

  const int chunk = (N + TPB - 1) / TPB;

  hipMemsetAsync(deg, 0, (size_t)N * 4, stream);
  deg_count_kernel<<<(E + TPB - 1) / TPB, TPB, 0, stream>>>(dstv, deg, E);
  dinv_kernel<<<(N + TPB - 1) / TPB, TPB, 0, stream>>>(deg, dinv, dinv2, N);
  scan_chunks_kernel<<<1, TPB, 0, stream>>>(deg, chunkbase, N, chunk);
  fill_rowptr_kernel<<<1, TPB, 0, stream>>>(deg, chunkbase, rowptr, cursor, N, E, chunk);
  csr_fill_kernel<<<(E + TPB - 1) / TPB, TPB, 0, stream>>>(srcv, dstv, dinv, cursor,
                                                           csr_src, csr_norm, E);

  // Layer 1: 128 -> 16   (x -> hA -> hB)
  matmul_kernel<128, 16><<<((size_t)N * 16 + TPB - 1) / TPB, TPB, 0, stream>>>(x, W1, hA, N);
  gather_agg_kernel<16><<<((size_t)N * 16 + TPB - 1) / TPB, TPB, 0, stream>>>(
      rowptr, csr_src, csr_norm, hA, dinv2, b1, hB, N);

  // Layer 2: 16 -> 24    (hB -> hA -> hB)
  matmul_kernel<16, 24><<<((size_t)N * 24 + TPB - 1) / TPB, TPB, 0, stream>>>(hB, W2, hA, N);
  gather_agg_kernel<24><<<((size_t)N * 24 + TPB - 1) / TPB, TPB, 0, stream>>>(
      rowptr, csr_src, csr_norm, hA, dinv2, b2, hB, N);

  // Layer 3: 24 -> 32    (hB -> hA -> hB)
  matmul_kernel<24, 32><<<((size_t)N * 32 + TPB - 1) / TPB, TPB, 0, stream>>>(hB, W3, hA, N);
  gather_agg_kernel<32><<<((size_t)N * 32 + TPB - 1) / TPB, TPB, 0, stream>>>(
      rowptr, csr_src, csr_norm, hA, dinv2, b3, hB, N);

  int* outI = (int*)d_out;

  // Start head: hid (N x 16) then pick
  hid_start_kernel<<<((size_t)N * 16 + TPB - 1) / TPB, TPB, 0, stream>>>(hB, Ws1, bs1, hid_start, N);
  pick_kernel<16><<<((size_t)N * 32 + TPB - 1) / TPB, TPB, 0, stream>>>(
      hid_start, Ws2, bs2, outI, N, k1a, k1b);

  // End head: hid (2N x 24) then pick
  hid_end_kernel<<<((size_t)2 * N * 24 + TPB - 1) / TPB, TPB, 0, stream>>>(hB, outI, We1, be1, hid_end, N);
  pick_kernel<24><<<((size_t)2 * N * 32 + TPB - 1) / TPB, TPB, 0, stream>>>(
      hid_end, We2, be2, outI + N, 2 * N, k2a, k2b);
}